// Round 1
// baseline (945.022 us; speedup 1.0000x reference)
//
#include <hip/hip_runtime.h>

// Problem constants
#define B_   64
#define S_   2048
#define E_   1024
#define H_   512
#define EMB_ 256
#define V_   50257
#define M_   (B_*S_)   // 131072 rows of the big GEMM

typedef __attribute__((ext_vector_type(8))) short bf16x8;   // 8 bf16 = 4 VGPR
typedef __attribute__((ext_vector_type(4))) float f32x4;

__device__ __forceinline__ unsigned short f2bf(float f) {
  unsigned int u = __float_as_uint(f);
  u += 0x7fffu + ((u >> 16) & 1u);          // round-to-nearest-even
  return (unsigned short)(u >> 16);
}
__device__ __forceinline__ float sigm(float x)  { return 1.f / (1.f + __expf(-x)); }
__device__ __forceinline__ float tanh_f(float x){ return 1.f - 2.f / (1.f + __expf(2.f * x)); } // graceful at +-inf

// ---------------------------------------------------------------------------
// K1a: attn_wh_w (512x1024 f32) -> bf16, linear [n][k]
__global__ __launch_bounds__(256) void k_convw(const float* __restrict__ w,
                                               unsigned short* __restrict__ wb) {
  int i = blockIdx.x * 256 + threadIdx.x;     // 2048 blocks * 256 = 524288
  wb[i] = f2bf(w[i]);
}

// K1b: wsb_tot[b][n] = attn_wh_b[n] + attn_ws_b[n] + sum_k h0[b][k]*attn_ws_w[n][k]
__global__ __launch_bounds__(256) void k_wsapp(const float* __restrict__ h0,
                                               const float* __restrict__ wsw,
                                               const float* __restrict__ wsb,
                                               const float* __restrict__ whb,
                                               float* __restrict__ outw) {
  int g = blockIdx.x * 256 + threadIdx.x;     // 128 blocks -> 32768 threads
  int b = g >> 9, n = g & 511;
  const float* hr = h0 + b * 512;
  const float* wr = wsw + (size_t)n * 512;
  float acc = 0.f;
  for (int k = 0; k < 512; k += 4) {
    float4 a = *(const float4*)(hr + k);
    float4 w = *(const float4*)(wr + k);
    acc += a.x*w.x + a.y*w.y + a.z*w.z + a.w*w.w;
  }
  outw[g] = acc + wsb[n] + whb[n];
}

// ---------------------------------------------------------------------------
// K2: fused energy GEMM.  ep[nc][m] = sum_{n in chunk nc} v[n]*tanh(enc[m]·W[n] + wsb[b][n])
#define BM 128
#define BN 128
#define BK 64
__global__ __launch_bounds__(256, 3) void k_energy(
    const float* __restrict__ enc, const unsigned short* __restrict__ Wb,
    const float* __restrict__ wsb, const float* __restrict__ av,
    float* __restrict__ ep)
{
  __shared__ unsigned short As[BM * BK];   // 16KB, 128B rows, XOR-swizzled
  __shared__ unsigned short Bs[BN * BK];   // 16KB
  __shared__ float red[2][BM];

  const int tid = threadIdx.x;
  const int bid = blockIdx.x;
  const int nc = bid & 3;          // n-chunk 0..3 (128 cols each)
  const int mt = bid >> 2;         // m-tile 0..1023
  const int m0 = mt * BM;
  const int n0 = nc * BN;
  const int bb = m0 >> 11;         // batch index (m-tiles never straddle b)

  const int wv = tid >> 6, lane = tid & 63;
  const int wm = wv >> 1, wn = wv & 1;      // wave tile 64x64
  const int lr = lane & 15, lg = lane >> 4;

  f32x4 acc[4][4];
  #pragma unroll
  for (int i = 0; i < 4; ++i)
    #pragma unroll
    for (int j = 0; j < 4; ++j)
      #pragma unroll
      for (int r = 0; r < 4; ++r) acc[i][j][r] = 0.f;

  const int ar = tid >> 4;          // 0..15
  const int ac = (tid & 15) << 2;   // 0..60 (float index)
  char* AsB = (char*)As;
  char* BsB = (char*)Bs;
  const char* WbB = (const char*)Wb;

  for (int kt = 0; kt < 16; ++kt) {
    const int k0 = kt * BK;
    // stage B (bf16, linear global read, swizzled LDS write)
    #pragma unroll
    for (int i = 0; i < 4; ++i) {
      int o = (i * 256 + tid) * 16;
      int n = o >> 7, x = o & 127;
      uint4 v = *(const uint4*)(WbB + (size_t)(n0 + n) * 2048 + k0 * 2 + x);
      *(uint4*)(BsB + n * 128 + (x ^ ((n & 7) << 4))) = v;
    }
    // stage A: fp32 -> bf16 convert
    #pragma unroll
    for (int i = 0; i < 8; ++i) {
      int row = ar + i * 16;
      float4 v = *(const float4*)(enc + (size_t)(m0 + row) * 1024 + k0 + ac);
      ushort4 p;
      p.x = f2bf(v.x); p.y = f2bf(v.y); p.z = f2bf(v.z); p.w = f2bf(v.w);
      *(ushort4*)(AsB + row * 128 + ((ac * 2) ^ ((row & 7) << 4))) = p;
    }
    __syncthreads();
    #pragma unroll
    for (int ks = 0; ks < 2; ++ks) {
      const int kb = ks * 64 + lg * 16;
      bf16x8 af[4];
      #pragma unroll
      for (int fm = 0; fm < 4; ++fm) {
        int row = wm * 64 + fm * 16 + lr;
        af[fm] = *(const bf16x8*)(AsB + row * 128 + (kb ^ ((lr & 7) << 4)));
      }
      #pragma unroll
      for (int fn = 0; fn < 4; ++fn) {
        int rn = wn * 64 + fn * 16 + lr;
        bf16x8 bf = *(const bf16x8*)(BsB + rn * 128 + (kb ^ ((lr & 7) << 4)));
        #pragma unroll
        for (int fm = 0; fm < 4; ++fm)
          acc[fm][fn] = __builtin_amdgcn_mfma_f32_16x16x32_bf16(af[fm], bf, acc[fm][fn], 0, 0, 0);
      }
    }
    __syncthreads();
  }

  // epilogue: e_row = sum_cols v[col]*tanh(acc + wsb[b][col]); deterministic reduce
  float cw_[4], cv_[4];
  #pragma unroll
  for (int fn = 0; fn < 4; ++fn) {
    int col = n0 + wn * 64 + fn * 16 + lr;
    cw_[fn] = wsb[bb * 512 + col];
    cv_[fn] = av[col];
  }
  #pragma unroll
  for (int fm = 0; fm < 4; ++fm) {
    float rs[4] = {0.f, 0.f, 0.f, 0.f};
    #pragma unroll
    for (int fn = 0; fn < 4; ++fn)
      #pragma unroll
      for (int r = 0; r < 4; ++r)
        rs[r] += cv_[fn] * tanh_f(acc[fm][fn][r] + cw_[fn]);   // C/D: row=(l>>4)*4+r, col=l&15
    #pragma unroll
    for (int r = 0; r < 4; ++r) {
      float v = rs[r];
      v += __shfl_xor(v, 1); v += __shfl_xor(v, 2);
      v += __shfl_xor(v, 4); v += __shfl_xor(v, 8);
      if (lr == 0) red[wn][wm * 64 + fm * 16 + lg * 4 + r] = v;
    }
  }
  __syncthreads();
  if (tid < BM)
    ep[(size_t)nc * M_ + m0 + tid] = red[0][tid] + red[1][tid];
}

// ---------------------------------------------------------------------------
// K3: softmax over S per batch.  attn[b][s]
__global__ __launch_bounds__(256) void k_attnsm(const float* __restrict__ ep,
                                                float* __restrict__ attn) {
  int b = blockIdx.x, tid = threadIdx.x;
  __shared__ float sm[256];
  float e[8]; float mx = -3.0e38f;
  #pragma unroll
  for (int i = 0; i < 8; ++i) {
    int m = b * 2048 + i * 256 + tid;
    float v = ep[m] + ep[M_ + m] + ep[2 * M_ + m] + ep[3 * M_ + m];
    e[i] = v; mx = fmaxf(mx, v);
  }
  sm[tid] = mx; __syncthreads();
  for (int st = 128; st; st >>= 1) { if (tid < st) sm[tid] = fmaxf(sm[tid], sm[tid + st]); __syncthreads(); }
  mx = sm[0]; __syncthreads();
  float sum = 0.f;
  #pragma unroll
  for (int i = 0; i < 8; ++i) { e[i] = __expf(e[i] - mx); sum += e[i]; }
  sm[tid] = sum; __syncthreads();
  for (int st = 128; st; st >>= 1) { if (tid < st) sm[tid] += sm[tid + st]; __syncthreads(); }
  float inv = 1.f / sm[0];
  #pragma unroll
  for (int i = 0; i < 8; ++i) attn[b * 2048 + i * 256 + tid] = e[i] * inv;
}

// K4: context partials. cp[sc][b][e] = sum_{s in chunk} attn[b][s]*enc[b][s][e]
__global__ __launch_bounds__(256) void k_ctx(const float* __restrict__ enc,
                                             const float* __restrict__ attn,
                                             float* __restrict__ cp) {
  int sc = blockIdx.x, b = blockIdx.y, tid = threadIdx.x;
  int e0 = tid * 4;
  float ax = 0.f, ay = 0.f, az = 0.f, aw = 0.f;
  const float* base = enc + ((size_t)b * 2048 + sc * 128) * 1024 + e0;
  const float* awt = attn + b * 2048 + sc * 128;
  #pragma unroll 4
  for (int s = 0; s < 128; ++s) {
    float w = awt[s];
    float4 v = *(const float4*)(base + (size_t)s * 1024);
    ax += w * v.x; ay += w * v.y; az += w * v.z; aw += w * v.w;
  }
  float4 o; o.x = ax; o.y = ay; o.z = az; o.w = aw;
  *(float4*)(cp + ((size_t)sc * 64 + b) * 1024 + e0) = o;
}

// K5a: reduce context, build xT[k][b] (k<1024 ctx, 1024..1279 embed, 1280..1791 h0),
//      and cw[b] = context·wh_vec + embed·wx_vec
__global__ __launch_bounds__(256) void k_xprep(const float* __restrict__ cp,
                                               const float* __restrict__ et,
                                               const int* __restrict__ dec,
                                               const float* __restrict__ h0,
                                               const float* __restrict__ whv,
                                               const float* __restrict__ wxv,
                                               float* __restrict__ xT,
                                               float* __restrict__ cw) {
  int b = blockIdx.x, tid = threadIdx.x;
  __shared__ float sm[256];
  float acc = 0.f;
  for (int j = tid; j < 1024; j += 256) {
    float s = 0.f;
    #pragma unroll
    for (int sc = 0; sc < 16; ++sc) s += cp[((size_t)sc * 64 + b) * 1024 + j];
    xT[j * 64 + b] = s;
    acc += s * whv[j];
  }
  int e = dec[b];
  {
    int j = tid;   // exactly 256 embed dims
    float s = et[(size_t)e * 256 + j];
    xT[(1024 + j) * 64 + b] = s;
    acc += s * wxv[j];
  }
  for (int j = tid; j < 512; j += 256)
    xT[(1280 + j) * 64 + b] = h0[b * 512 + j];
  sm[tid] = acc; __syncthreads();
  for (int st = 128; st; st >>= 1) { if (tid < st) sm[tid] += sm[tid + st]; __syncthreads(); }
  if (!tid) cw[b] = sm[0];
}

// K5b: gate partials. gp[kc][b][j] = sum_{k in chunk} W[j][k]*x[b][k]
__global__ __launch_bounds__(256) void k_gates(const float* __restrict__ wih,
                                               const float* __restrict__ whh,
                                               const float* __restrict__ xT,
                                               float* __restrict__ gp) {
  int jt = blockIdx.x, kc = blockIdx.y;
  int j = jt * 256 + (int)threadIdx.x;
  const float* wr = (kc < 10) ? (wih + (size_t)j * 1280 + kc * 128)
                              : (whh + (size_t)j * 512 + (kc - 10) * 128);
  const float* xbase = xT + (size_t)kc * 128 * 64;
  float acc[64];
  #pragma unroll
  for (int i = 0; i < 64; ++i) acc[i] = 0.f;
  for (int k = 0; k < 128; k += 4) {
    float4 w4 = *(const float4*)(wr + k);
    #pragma unroll
    for (int kk = 0; kk < 4; ++kk) {
      float wv = (kk == 0) ? w4.x : (kk == 1) ? w4.y : (kk == 2) ? w4.z : w4.w;
      const float* xr = xbase + (size_t)(k + kk) * 64;
      #pragma unroll
      for (int b4 = 0; b4 < 16; ++b4) {
        float4 x4 = *(const float4*)(xr + b4 * 4);     // uniform -> scalar loads
        acc[b4 * 4 + 0] += wv * x4.x; acc[b4 * 4 + 1] += wv * x4.y;
        acc[b4 * 4 + 2] += wv * x4.z; acc[b4 * 4 + 3] += wv * x4.w;
      }
    }
  }
  float* gout = gp + (size_t)kc * 64 * 2048 + j;
  #pragma unroll
  for (int b = 0; b < 64; ++b) gout[(size_t)b * 2048] = acc[b];
}

// K5c: LSTM cell + h_t,c_t outputs + p_gen
__global__ __launch_bounds__(512) void k_lstm(const float* __restrict__ gp,
                                              const float* __restrict__ bih,
                                              const float* __restrict__ bhh,
                                              const float* __restrict__ c0,
                                              const float* __restrict__ cw,
                                              const float* __restrict__ wsv,
                                              float* __restrict__ dout,
                                              float* __restrict__ pg) {
  int b = blockIdx.x, h = threadIdx.x;
  __shared__ float sm[512];
  float gi = bih[h]        + bhh[h];
  float gf = bih[512 + h]  + bhh[512 + h];
  float gg = bih[1024 + h] + bhh[1024 + h];
  float go = bih[1536 + h] + bhh[1536 + h];
  for (int kc = 0; kc < 14; ++kc) {
    const float* g = gp + ((size_t)kc * 64 + b) * 2048;
    gi += g[h]; gf += g[512 + h]; gg += g[1024 + h]; go += g[1536 + h];
  }
  float c  = sigm(gf) * c0[b * 512 + h] + sigm(gi) * tanh_f(gg);
  float ht = sigm(go) * tanh_f(c);
  dout[(size_t)B_ * V_ + b * 512 + h] = ht;
  dout[(size_t)B_ * V_ + B_ * H_ + b * 512 + h] = c;
  sm[h] = ht * wsv[h];
  __syncthreads();
  for (int st = 256; st; st >>= 1) { if (h < st) sm[h] += sm[h + st]; __syncthreads(); }
  if (!h) pg[b] = sigm(cw[b] + sm[0]);
}

// K6: vocab logits. out[b][v] = h_t[b]·v_w[v] + v_b[v]
__global__ __launch_bounds__(256) void k_logits(const float* __restrict__ vw,
                                                const float* __restrict__ vb,
                                                const float* __restrict__ ht,
                                                float* __restrict__ out) {
  int v = blockIdx.x * 256 + threadIdx.x;
  bool ok = v < V_;
  int vc = ok ? v : 0;
  const float* wr = vw + (size_t)vc * 512;
  float acc[64];
  #pragma unroll
  for (int b = 0; b < 64; ++b) acc[b] = 0.f;
  for (int k = 0; k < 512; k += 4) {
    float4 w4 = *(const float4*)(wr + k);
    #pragma unroll
    for (int b = 0; b < 64; ++b) {
      float4 h4 = *(const float4*)(ht + b * 512 + k);   // uniform -> s_load
      acc[b] += w4.x * h4.x + w4.y * h4.y + w4.z * h4.z + w4.w * h4.w;
    }
  }
  if (ok) {
    float bb = vb[v];
    #pragma unroll
    for (int b = 0; b < 64; ++b) out[(size_t)b * V_ + v] = acc[b] + bb;
  }
}

// K7: per-batch softmax stats over V
__global__ __launch_bounds__(256) void k_smstats(const float* __restrict__ out,
                                                 float* __restrict__ stats) {
  int b = blockIdx.x, tid = threadIdx.x;
  __shared__ float sm[256];
  const float* row = out + (size_t)b * V_;
  float mx = -3.0e38f;
  for (int v = tid; v < V_; v += 256) mx = fmaxf(mx, row[v]);
  sm[tid] = mx; __syncthreads();
  for (int st = 128; st; st >>= 1) { if (tid < st) sm[tid] = fmaxf(sm[tid], sm[tid + st]); __syncthreads(); }
  mx = sm[0]; __syncthreads();
  float sum = 0.f;
  for (int v = tid; v < V_; v += 256) sum += __expf(row[v] - mx);
  sm[tid] = sum; __syncthreads();
  for (int st = 128; st; st >>= 1) { if (tid < st) sm[tid] += sm[tid + st]; __syncthreads(); }
  if (!tid) { stats[b * 2] = mx; stats[b * 2 + 1] = sm[0]; }
}

// K8: out = p_gen * softmax(logits) in place
__global__ __launch_bounds__(256) void k_final(float* __restrict__ out,
                                               const float* __restrict__ stats,
                                               const float* __restrict__ pg) {
  int v = blockIdx.x * 256 + threadIdx.x;
  int b = blockIdx.y;
  if (v < V_) {
    float mx = stats[b * 2];
    float scale = pg[b] / stats[b * 2 + 1];
    size_t i = (size_t)b * V_ + v;
    out[i] = scale * __expf(out[i] - mx);
  }
}

// K9: out[b][enc_inputs[b][s]] += (1-p_gen[b]) * attn[b][s]
__global__ __launch_bounds__(256) void k_scatter(float* __restrict__ out,
                                                 const float* __restrict__ attn,
                                                 const int* __restrict__ einp,
                                                 const float* __restrict__ pg) {
  int b = blockIdx.y;
  int s = blockIdx.x * 256 + threadIdx.x;
  int v = einp[b * 2048 + s];
  float w = (1.f - pg[b]) * attn[b * 2048 + s];
  atomicAdd(out + (size_t)b * V_ + v, w);
}

// ---------------------------------------------------------------------------
extern "C" void kernel_launch(void* const* d_in, const int* in_sizes, int n_in,
                              void* d_out, int out_size, void* d_ws, size_t ws_size,
                              hipStream_t stream) {
  const float* enc  = (const float*)d_in[0];
  const float* h0   = (const float*)d_in[1];
  const float* c0   = (const float*)d_in[2];
  const int*   dec  = (const int*)d_in[3];
  const int*   einp = (const int*)d_in[4];
  const float* et   = (const float*)d_in[5];
  const float* whw  = (const float*)d_in[6];
  const float* whb  = (const float*)d_in[7];
  const float* wsw  = (const float*)d_in[8];
  const float* wsbv = (const float*)d_in[9];
  const float* av   = (const float*)d_in[10];
  const float* wih  = (const float*)d_in[11];
  const float* whh  = (const float*)d_in[12];
  const float* bih  = (const float*)d_in[13];
  const float* bhh  = (const float*)d_in[14];
  const float* whv  = (const float*)d_in[15];
  const float* wsv  = (const float*)d_in[16];
  const float* wxv  = (const float*)d_in[17];
  const float* vw   = (const float*)d_in[18];
  const float* vb   = (const float*)d_in[19];
  float* out = (float*)d_out;

  char* ws = (char*)d_ws;                      // ~15.1 MB used
  unsigned short* Wb = (unsigned short*)(ws + 0);        // 1,048,576 B
  float* wsbt  = (float*)(ws + 1048576);                 //   131,072 B
  float* ep    = (float*)(ws + 1179648);                 // 2,097,152 B (4 x M_)
  float* attn  = (float*)(ws + 3276800);                 //   524,288 B
  float* cp    = (float*)(ws + 3801088);                 // 4,194,304 B
  float* xT    = (float*)(ws + 7995392);                 //   458,752 B
  float* cw    = (float*)(ws + 8454144);                 //       256 B
  float* pg    = (float*)(ws + 8454400);                 //       256 B
  float* stats = (float*)(ws + 8454656);                 //       512 B
  float* gp    = (float*)(ws + 8455168);                 // 7,340,032 B

  k_convw  <<<2048, 256, 0, stream>>>(whw, Wb);
  k_wsapp  <<<128, 256, 0, stream>>>(h0, wsw, wsbv, whb, wsbt);
  k_energy <<<4096, 256, 0, stream>>>(enc, Wb, wsbt, av, ep);
  k_attnsm <<<64, 256, 0, stream>>>(ep, attn);
  k_ctx    <<<dim3(16, 64), 256, 0, stream>>>(enc, attn, cp);
  k_xprep  <<<64, 256, 0, stream>>>(cp, et, dec, h0, whv, wxv, xT, cw);
  k_gates  <<<dim3(8, 14), 256, 0, stream>>>(wih, whh, xT, gp);
  k_lstm   <<<64, 512, 0, stream>>>(gp, bih, bhh, c0, cw, wsv, out, pg);
  k_logits <<<197, 256, 0, stream>>>(vw, vb, out + (size_t)B_ * V_, out);
  k_smstats<<<64, 256, 0, stream>>>(out, stats);
  k_final  <<<dim3(197, 64), 256, 0, stream>>>(out, stats, pg);
  k_scatter<<<dim3(8, 64), 256, 0, stream>>>(out, attn, einp, pg);
}

// Round 2
// 896.007 us; speedup vs baseline: 1.0547x; 1.0547x over previous
//
#include <hip/hip_runtime.h>

// Problem constants
#define B_   64
#define S_   2048
#define E_   1024
#define H_   512
#define EMB_ 256
#define V_   50257
#define M_   (B_*S_)

typedef __attribute__((ext_vector_type(8))) short bf16x8;   // 8 bf16 = 4 VGPR
typedef __attribute__((ext_vector_type(4))) float f32x4;

__device__ __forceinline__ unsigned short f2bf(float f) {
  unsigned int u = __float_as_uint(f);
  u += 0x7fffu + ((u >> 16) & 1u);          // round-to-nearest-even
  return (unsigned short)(u >> 16);
}
__device__ __forceinline__ float sigm(float x)  { return 1.f / (1.f + __expf(-x)); }
__device__ __forceinline__ float tanh_f(float x){ return 1.f - 2.f / (1.f + __expf(2.f * x)); }

// ---------------------------------------------------------------------------
// K1a: attn_wh_w (512x1024 f32) -> bf16 in MFMA-native layout Wb[kq][n][8]
//      element i = kq*4096 + n*8 + kd  <-  whw[n][kq*8+kd]
__global__ __launch_bounds__(256) void k_convw(const float* __restrict__ w,
                                               unsigned short* __restrict__ wb) {
  int i = blockIdx.x * 256 + threadIdx.x;     // 524288
  int kq = i >> 12;
  int r  = i & 4095;
  int n  = r >> 3;
  int kd = r & 7;
  wb[i] = f2bf(w[((size_t)n << 10) + (kq << 3) + kd]);
}

// K1b: wsb_tot[b][n] = attn_wh_b[n] + attn_ws_b[n] + h0[b]·attn_ws_w[n]
__global__ __launch_bounds__(256) void k_wsapp(const float* __restrict__ h0,
                                               const float* __restrict__ wsw,
                                               const float* __restrict__ wsb,
                                               const float* __restrict__ whb,
                                               float* __restrict__ outw) {
  int g = blockIdx.x * 256 + threadIdx.x;
  int b = g >> 9, n = g & 511;
  const float* hr = h0 + b * 512;
  const float* wr = wsw + (size_t)n * 512;
  float acc = 0.f;
  for (int k = 0; k < 512; k += 4) {
    float4 a = *(const float4*)(hr + k);
    float4 w = *(const float4*)(wr + k);
    acc += a.x*w.x + a.y*w.y + a.z*w.z + a.w*w.w;
  }
  outw[g] = acc + wsb[n] + whb[n];
}

// ---------------------------------------------------------------------------
// K2: fused energy GEMM. Block = 128 rows x full N=512; enc fetched exactly once.
//     e[m] = sum_n av[n] * tanh(enc[m]·W[n] + wsb[b][n])
__global__ __launch_bounds__(512, 2) void k_energy(
    const float* __restrict__ enc, const unsigned short* __restrict__ Wb,
    const float* __restrict__ wsb, const float* __restrict__ av,
    float* __restrict__ eout)
{
  __shared__ __attribute__((aligned(16))) unsigned short As[128 * 128]; // 32 KB: [row][k-slab 128], swizzled
  __shared__ __attribute__((aligned(16))) unsigned short Bs[2][16384];  // 2x32 KB: [kq(4)][n(512)][8]
  __shared__ float red[4][128];

  const int tid  = threadIdx.x;
  const int w    = tid >> 6;
  const int lane = tid & 63;
  const int lr   = lane & 15, lg = lane >> 4;
  const int wm   = w >> 2, wn = w & 3;        // wave grid 2(m) x 4(n), wave tile 64x128
  const int m0   = blockIdx.x * 128;
  const int bb   = m0 >> 11;                  // batch (128 | 2048, never straddles)

  f32x4 acc[4][8];
  #pragma unroll
  for (int i = 0; i < 4; ++i)
    #pragma unroll
    for (int j = 0; j < 8; ++j)
      #pragma unroll
      for (int r = 0; r < 4; ++r) acc[i][j][r] = 0.f;

  char* AsB = (char*)As;

  // A chunk mapping: c = i*512+tid; row=c>>4 (128 rows), kq=c&15 (16 chunks of 8k)
  float4 a0[4], a1[4];
  auto issueA = [&](int s) {
    #pragma unroll
    for (int i = 0; i < 4; ++i) {
      int c = i * 512 + tid;
      int row = c >> 4, kq = c & 15;
      const float* gp = enc + ((size_t)(m0 + row) << 10) + (s << 7) + (kq << 3);
      a0[i] = *(const float4*)gp;
      a1[i] = *(const float4*)(gp + 4);
    }
  };
  auto writeA = [&]() {
    #pragma unroll
    for (int i = 0; i < 4; ++i) {
      int c = i * 512 + tid;
      int row = c >> 4, kq = c & 15;
      uint4 pv;
      pv.x = (unsigned)f2bf(a0[i].x) | ((unsigned)f2bf(a0[i].y) << 16);
      pv.y = (unsigned)f2bf(a0[i].z) | ((unsigned)f2bf(a0[i].w) << 16);
      pv.z = (unsigned)f2bf(a1[i].x) | ((unsigned)f2bf(a1[i].y) << 16);
      pv.w = (unsigned)f2bf(a1[i].z) | ((unsigned)f2bf(a1[i].w) << 16);
      *(uint4*)(AsB + row * 256 + ((kq * 16) ^ ((row & 7) << 4))) = pv;
    }
  };

  uint4 bv[4];
  auto issueB = [&](int kt) {
    const uint4* g = (const uint4*)(Wb + kt * 16384) + tid;
    #pragma unroll
    for (int i = 0; i < 4; ++i) bv[i] = g[i * 512];
  };
  auto writeB = [&](int d) {
    uint4* p = (uint4*)(&Bs[d][0]) + tid;
    #pragma unroll
    for (int i = 0; i < 4; ++i) p[i * 512] = bv[i];
  };

  // precomputed fragment addresses
  int arow256[4], aswz[4];
  #pragma unroll
  for (int fm = 0; fm < 4; ++fm) {
    int row = wm * 64 + fm * 16 + lr;
    arow256[fm] = row * 256;
    aswz[fm] = (row & 7) << 4;
  }
  int boff[8];
  #pragma unroll
  for (int fn = 0; fn < 8; ++fn)
    boff[fn] = lg * 8192 + (wn * 128 + fn * 16 + lr) * 16;

  // prologue: slab 0 + B tile 0
  issueA(0);
  writeA();
  issueB(0);
  writeB(0);
  __syncthreads();

  for (int kt = 0; kt < 32; ++kt) {
    const int buf = kt & 1;
    if (kt < 31) issueB(kt + 1);                       // issue-early (dbuf)
    if ((kt & 3) == 2 && kt < 28) issueA((kt >> 2) + 1); // T14: A-slab loads 1-2 phases ahead

    const int klo = (kt & 3) * 64 + lg * 16;           // byte offset within A row
    bf16x8 af[4];
    #pragma unroll
    for (int fm = 0; fm < 4; ++fm)
      af[fm] = *(const bf16x8*)(AsB + arow256[fm] + (klo ^ aswz[fm]));
    #pragma unroll
    for (int fn = 0; fn < 8; ++fn) {
      bf16x8 bf = *(const bf16x8*)((char*)&Bs[buf][0] + boff[fn]);
      #pragma unroll
      for (int fm = 0; fm < 4; ++fm)
        acc[fm][fn] = __builtin_amdgcn_mfma_f32_16x16x32_bf16(af[fm], bf, acc[fm][fn], 0, 0, 0);
    }
    if (kt < 31) writeB(buf ^ 1);                      // write-late into idle buffer
    if ((kt & 3) == 3 && kt < 31) {                    // slab boundary: restage A
      __syncthreads();
      writeA();
    }
    __syncthreads();
  }

  // epilogue: e_row = sum_cols av[col]*tanh(acc + wsb[b][col]); deterministic reduce
  float cw_[8], cv_[8];
  #pragma unroll
  for (int fn = 0; fn < 8; ++fn) {
    int col = wn * 128 + fn * 16 + lr;
    cw_[fn] = wsb[bb * 512 + col];
    cv_[fn] = av[col];
  }
  #pragma unroll
  for (int fm = 0; fm < 4; ++fm) {
    #pragma unroll
    for (int r = 0; r < 4; ++r) {
      float v = 0.f;
      #pragma unroll
      for (int fn = 0; fn < 8; ++fn)
        v += cv_[fn] * tanh_f(acc[fm][fn][r] + cw_[fn]);   // C/D: col=lane&15, row=(lane>>4)*4+r
      v += __shfl_xor(v, 1); v += __shfl_xor(v, 2);
      v += __shfl_xor(v, 4); v += __shfl_xor(v, 8);
      if (lr == 0) red[wn][wm * 64 + fm * 16 + lg * 4 + r] = v;
    }
  }
  __syncthreads();
  if (tid < 128)
    eout[m0 + tid] = red[0][tid] + red[1][tid] + red[2][tid] + red[3][tid];
}

// ---------------------------------------------------------------------------
// K3: softmax over S per batch
__global__ __launch_bounds__(256) void k_attnsm(const float* __restrict__ e,
                                                float* __restrict__ attn) {
  int b = blockIdx.x, tid = threadIdx.x;
  __shared__ float sm[256];
  float ev[8]; float mx = -3.0e38f;
  #pragma unroll
  for (int i = 0; i < 8; ++i) {
    float v = e[b * 2048 + i * 256 + tid];
    ev[i] = v; mx = fmaxf(mx, v);
  }
  sm[tid] = mx; __syncthreads();
  for (int st = 128; st; st >>= 1) { if (tid < st) sm[tid] = fmaxf(sm[tid], sm[tid + st]); __syncthreads(); }
  mx = sm[0]; __syncthreads();
  float sum = 0.f;
  #pragma unroll
  for (int i = 0; i < 8; ++i) { ev[i] = __expf(ev[i] - mx); sum += ev[i]; }
  sm[tid] = sum; __syncthreads();
  for (int st = 128; st; st >>= 1) { if (tid < st) sm[tid] += sm[tid + st]; __syncthreads(); }
  float inv = 1.f / sm[0];
  #pragma unroll
  for (int i = 0; i < 8; ++i) attn[b * 2048 + i * 256 + tid] = ev[i] * inv;
}

// K4: context partials over 32 s-chunks of 64
__global__ __launch_bounds__(256) void k_ctx(const float* __restrict__ enc,
                                             const float* __restrict__ attn,
                                             float* __restrict__ cp) {
  int sc = blockIdx.x, b = blockIdx.y, tid = threadIdx.x;
  int e0 = tid * 4;
  float ax = 0.f, ay = 0.f, az = 0.f, aw = 0.f;
  const float* base = enc + ((size_t)b * 2048 + sc * 64) * 1024 + e0;
  const float* awt = attn + b * 2048 + sc * 64;
  #pragma unroll 8
  for (int s = 0; s < 64; ++s) {
    float wv = awt[s];
    float4 v = *(const float4*)(base + (size_t)s * 1024);
    ax += wv * v.x; ay += wv * v.y; az += wv * v.z; aw += wv * v.w;
  }
  float4 o; o.x = ax; o.y = ay; o.z = az; o.w = aw;
  *(float4*)(cp + ((size_t)sc * 64 + b) * 1024 + e0) = o;
}

// K5a: reduce context, build xT[k][b], cw[b] = ctx·wh_vec + embed·wx_vec
__global__ __launch_bounds__(256) void k_xprep(const float* __restrict__ cp,
                                               const float* __restrict__ et,
                                               const int* __restrict__ dec,
                                               const float* __restrict__ h0,
                                               const float* __restrict__ whv,
                                               const float* __restrict__ wxv,
                                               float* __restrict__ xT,
                                               float* __restrict__ cw) {
  int b = blockIdx.x, tid = threadIdx.x;
  __shared__ float sm[256];
  float acc = 0.f;
  for (int j = tid; j < 1024; j += 256) {
    float s = 0.f;
    #pragma unroll
    for (int sc = 0; sc < 32; ++sc) s += cp[((size_t)sc * 64 + b) * 1024 + j];
    xT[j * 64 + b] = s;
    acc += s * whv[j];
  }
  int e = dec[b];
  {
    int j = tid;
    float s = et[(size_t)e * 256 + j];
    xT[(1024 + j) * 64 + b] = s;
    acc += s * wxv[j];
  }
  for (int j = tid; j < 512; j += 256)
    xT[(1280 + j) * 64 + b] = h0[b * 512 + j];
  sm[tid] = acc; __syncthreads();
  for (int st = 128; st; st >>= 1) { if (tid < st) sm[tid] += sm[tid + st]; __syncthreads(); }
  if (!tid) cw[b] = sm[0];
}

// K5b: gate partials
__global__ __launch_bounds__(256) void k_gates(const float* __restrict__ wih,
                                               const float* __restrict__ whh,
                                               const float* __restrict__ xT,
                                               float* __restrict__ gp) {
  int jt = blockIdx.x, kc = blockIdx.y;
  int j = jt * 256 + (int)threadIdx.x;
  const float* wr = (kc < 10) ? (wih + (size_t)j * 1280 + kc * 128)
                              : (whh + (size_t)j * 512 + (kc - 10) * 128);
  const float* xbase = xT + (size_t)kc * 128 * 64;
  float acc[64];
  #pragma unroll
  for (int i = 0; i < 64; ++i) acc[i] = 0.f;
  for (int k = 0; k < 128; k += 4) {
    float4 w4 = *(const float4*)(wr + k);
    #pragma unroll
    for (int kk = 0; kk < 4; ++kk) {
      float wv = (kk == 0) ? w4.x : (kk == 1) ? w4.y : (kk == 2) ? w4.z : w4.w;
      const float* xr = xbase + (size_t)(k + kk) * 64;
      #pragma unroll
      for (int b4 = 0; b4 < 16; ++b4) {
        float4 x4 = *(const float4*)(xr + b4 * 4);
        acc[b4 * 4 + 0] += wv * x4.x; acc[b4 * 4 + 1] += wv * x4.y;
        acc[b4 * 4 + 2] += wv * x4.z; acc[b4 * 4 + 3] += wv * x4.w;
      }
    }
  }
  float* gout = gp + (size_t)kc * 64 * 2048 + j;
  #pragma unroll
  for (int b = 0; b < 64; ++b) gout[(size_t)b * 2048] = acc[b];
}

// K5c: LSTM cell + h_t,c_t outputs + p_gen
__global__ __launch_bounds__(512) void k_lstm(const float* __restrict__ gp,
                                              const float* __restrict__ bih,
                                              const float* __restrict__ bhh,
                                              const float* __restrict__ c0,
                                              const float* __restrict__ cw,
                                              const float* __restrict__ wsv,
                                              float* __restrict__ dout,
                                              float* __restrict__ pg) {
  int b = blockIdx.x, h = threadIdx.x;
  __shared__ float sm[512];
  float gi = bih[h]        + bhh[h];
  float gf = bih[512 + h]  + bhh[512 + h];
  float gg = bih[1024 + h] + bhh[1024 + h];
  float go = bih[1536 + h] + bhh[1536 + h];
  for (int kc = 0; kc < 14; ++kc) {
    const float* g = gp + ((size_t)kc * 64 + b) * 2048;
    gi += g[h]; gf += g[512 + h]; gg += g[1024 + h]; go += g[1536 + h];
  }
  float c  = sigm(gf) * c0[b * 512 + h] + sigm(gi) * tanh_f(gg);
  float ht = sigm(go) * tanh_f(c);
  dout[(size_t)B_ * V_ + b * 512 + h] = ht;
  dout[(size_t)B_ * V_ + B_ * H_ + b * 512 + h] = c;
  sm[h] = ht * wsv[h];
  __syncthreads();
  for (int st = 256; st; st >>= 1) { if (h < st) sm[h] += sm[h + st]; __syncthreads(); }
  if (!h) pg[b] = sigm(cw[b] + sm[0]);
}

// K6: vocab logits
__global__ __launch_bounds__(256) void k_logits(const float* __restrict__ vw,
                                                const float* __restrict__ vb,
                                                const float* __restrict__ ht,
                                                float* __restrict__ out) {
  int v = blockIdx.x * 256 + threadIdx.x;
  bool ok = v < V_;
  int vc = ok ? v : 0;
  const float* wr = vw + (size_t)vc * 512;
  float acc[64];
  #pragma unroll
  for (int b = 0; b < 64; ++b) acc[b] = 0.f;
  for (int k = 0; k < 512; k += 4) {
    float4 w4 = *(const float4*)(wr + k);
    #pragma unroll
    for (int b = 0; b < 64; ++b) {
      float4 h4 = *(const float4*)(ht + b * 512 + k);
      acc[b] += w4.x * h4.x + w4.y * h4.y + w4.z * h4.z + w4.w * h4.w;
    }
  }
  if (ok) {
    float bb = vb[v];
    #pragma unroll
    for (int b = 0; b < 64; ++b) out[(size_t)b * V_ + v] = acc[b] + bb;
  }
}

// K7a: per-(chunk,batch) softmax partials over V
#define VCH 6283
__global__ __launch_bounds__(256) void k_sm1(const float* __restrict__ out,
                                             float* __restrict__ pst) {
  int c = blockIdx.x, b = blockIdx.y, tid = threadIdx.x;
  __shared__ float sm[256];
  const float* row = out + (size_t)b * V_;
  int v0 = c * VCH, v1 = min(v0 + VCH, V_);
  float mx = -3.0e38f;
  for (int v = v0 + tid; v < v1; v += 256) mx = fmaxf(mx, row[v]);
  sm[tid] = mx; __syncthreads();
  for (int st = 128; st; st >>= 1) { if (tid < st) sm[tid] = fmaxf(sm[tid], sm[tid + st]); __syncthreads(); }
  mx = sm[0]; __syncthreads();
  float sum = 0.f;
  for (int v = v0 + tid; v < v1; v += 256) sum += __expf(row[v] - mx);
  sm[tid] = sum; __syncthreads();
  for (int st = 128; st; st >>= 1) { if (tid < st) sm[tid] += sm[tid + st]; __syncthreads(); }
  if (!tid) { pst[(b * 8 + c) * 2] = mx; pst[(b * 8 + c) * 2 + 1] = sm[0]; }
}

// K7b: merge chunk partials
__global__ __launch_bounds__(64) void k_sm2(const float* __restrict__ pst,
                                            float* __restrict__ stats) {
  int b = threadIdx.x;
  float mx = -3.0e38f;
  #pragma unroll
  for (int c = 0; c < 8; ++c) mx = fmaxf(mx, pst[(b * 8 + c) * 2]);
  float s = 0.f;
  #pragma unroll
  for (int c = 0; c < 8; ++c)
    s += pst[(b * 8 + c) * 2 + 1] * __expf(pst[(b * 8 + c) * 2] - mx);
  stats[b * 2] = mx; stats[b * 2 + 1] = s;
}

// K8: out = p_gen * softmax(logits) in place
__global__ __launch_bounds__(256) void k_final(float* __restrict__ out,
                                               const float* __restrict__ stats,
                                               const float* __restrict__ pg) {
  int v = blockIdx.x * 256 + threadIdx.x;
  int b = blockIdx.y;
  if (v < V_) {
    float mx = stats[b * 2];
    float scale = pg[b] / stats[b * 2 + 1];
    size_t i = (size_t)b * V_ + v;
    out[i] = scale * __expf(out[i] - mx);
  }
}

// K9: scatter attention into vocab
__global__ __launch_bounds__(256) void k_scatter(float* __restrict__ out,
                                                 const float* __restrict__ attn,
                                                 const int* __restrict__ einp,
                                                 const float* __restrict__ pg) {
  int b = blockIdx.y;
  int s = blockIdx.x * 256 + threadIdx.x;
  int v = einp[b * 2048 + s];
  float w = (1.f - pg[b]) * attn[b * 2048 + s];
  atomicAdd(out + (size_t)b * V_ + v, w);
}

// ---------------------------------------------------------------------------
extern "C" void kernel_launch(void* const* d_in, const int* in_sizes, int n_in,
                              void* d_out, int out_size, void* d_ws, size_t ws_size,
                              hipStream_t stream) {
  const float* enc  = (const float*)d_in[0];
  const float* h0   = (const float*)d_in[1];
  const float* c0   = (const float*)d_in[2];
  const int*   dec  = (const int*)d_in[3];
  const int*   einp = (const int*)d_in[4];
  const float* et   = (const float*)d_in[5];
  const float* whw  = (const float*)d_in[6];
  const float* whb  = (const float*)d_in[7];
  const float* wsw  = (const float*)d_in[8];
  const float* wsbv = (const float*)d_in[9];
  const float* av   = (const float*)d_in[10];
  const float* wih  = (const float*)d_in[11];
  const float* whh  = (const float*)d_in[12];
  const float* bih  = (const float*)d_in[13];
  const float* bhh  = (const float*)d_in[14];
  const float* whv  = (const float*)d_in[15];
  const float* wsv  = (const float*)d_in[16];
  const float* wxv  = (const float*)d_in[17];
  const float* vw   = (const float*)d_in[18];
  const float* vb   = (const float*)d_in[19];
  float* out = (float*)d_out;

  char* ws = (char*)d_ws;                                // ~11.1 MB used
  unsigned short* Wb = (unsigned short*)(ws + 0);        // 1,048,576
  float* wsbt  = (float*)(ws + 1048576);                 //   131,072
  float* e     = (float*)(ws + 1179648);                 //   524,288
  float* attn  = (float*)(ws + 1703936);                 //   524,288
  float* cpgp  = (float*)(ws + 2228224);                 // 8,388,608 (cp then gp, disjoint lifetimes)
  float* xT    = (float*)(ws + 10616832);                //   458,752
  float* cw    = (float*)(ws + 11075584);                //       256
  float* pg    = (float*)(ws + 11075840);                //       256
  float* stats = (float*)(ws + 11076096);                //       512
  float* pst   = (float*)(ws + 11076608);                //     4,096

  k_convw  <<<2048, 256, 0, stream>>>(whw, Wb);
  k_wsapp  <<<128, 256, 0, stream>>>(h0, wsw, wsbv, whb, wsbt);
  k_energy <<<1024, 512, 0, stream>>>(enc, Wb, wsbt, av, e);
  k_attnsm <<<64, 256, 0, stream>>>(e, attn);
  k_ctx    <<<dim3(32, 64), 256, 0, stream>>>(enc, attn, cpgp);
  k_xprep  <<<64, 256, 0, stream>>>(cpgp, et, dec, h0, whv, wxv, xT, cw);
  k_gates  <<<dim3(8, 14), 256, 0, stream>>>(wih, whh, xT, cpgp);
  k_lstm   <<<64, 512, 0, stream>>>(cpgp, bih, bhh, c0, cw, wsv, out, pg);
  k_logits <<<197, 256, 0, stream>>>(vw, vb, out + (size_t)B_ * V_, out);
  k_sm1    <<<dim3(8, 64), 256, 0, stream>>>(out, pst);
  k_sm2    <<<1, 64, 0, stream>>>(pst, stats);
  k_final  <<<dim3(197, 64), 256, 0, stream>>>(out, stats, pg);
  k_scatter<<<dim3(8, 64), 256, 0, stream>>>(out, attn, einp, pg);
}

// Round 3
// 537.297 us; speedup vs baseline: 1.7588x; 1.6676x over previous
//
#include <hip/hip_runtime.h>

// Problem constants
#define B_   64
#define S_   2048
#define E_   1024
#define H_   512
#define EMB_ 256
#define V_   50257
#define M_   (B_*S_)

typedef __attribute__((ext_vector_type(8))) short bf16x8;   // 8 bf16 = 4 VGPR
typedef __attribute__((ext_vector_type(4))) float f32x4;

__device__ __forceinline__ unsigned short f2bf(float f) {
  unsigned int u = __float_as_uint(f);
  u += 0x7fffu + ((u >> 16) & 1u);          // round-to-nearest-even
  return (unsigned short)(u >> 16);
}
__device__ __forceinline__ unsigned pk2(float a, float b) {
  return (unsigned)f2bf(a) | ((unsigned)f2bf(b) << 16);
}
__device__ __forceinline__ float sigm(float x)  { return 1.f / (1.f + __expf(-x)); }
__device__ __forceinline__ float tanh_f(float x){ return 1.f - 2.f / (1.f + __expf(2.f * x)); }

// ---------------------------------------------------------------------------
// K1a: attn_wh_w (512x1024 f32) -> bf16 in MFMA-native layout Wb[kq][n][8]
__global__ __launch_bounds__(256) void k_convw(const float* __restrict__ w,
                                               unsigned short* __restrict__ wb) {
  int i = blockIdx.x * 256 + threadIdx.x;     // 524288
  int kq = i >> 12;
  int r  = i & 4095;
  int n  = r >> 3;
  int kd = r & 7;
  wb[i] = f2bf(w[((size_t)n << 10) + (kq << 3) + kd]);
}

// K1b: wsb_tot[b][n] = attn_wh_b[n] + attn_ws_b[n] + h0[b]·attn_ws_w[n]
__global__ __launch_bounds__(256) void k_wsapp(const float* __restrict__ h0,
                                               const float* __restrict__ wsw,
                                               const float* __restrict__ wsb,
                                               const float* __restrict__ whb,
                                               float* __restrict__ outw) {
  int g = blockIdx.x * 256 + threadIdx.x;
  int b = g >> 9, n = g & 511;
  const float* hr = h0 + b * 512;
  const float* wr = wsw + (size_t)n * 512;
  float acc = 0.f;
  for (int k = 0; k < 512; k += 4) {
    float4 a = *(const float4*)(hr + k);
    float4 w = *(const float4*)(wr + k);
    acc += a.x*w.x + a.y*w.y + a.z*w.z + a.w*w.w;
  }
  outw[g] = acc + wsb[n] + whb[n];
}

// ---------------------------------------------------------------------------
// K2: fused energy GEMM. Block = 128 rows x full N=512; enc fetched exactly once.
__global__ __launch_bounds__(512, 2) void k_energy(
    const float* __restrict__ enc, const unsigned short* __restrict__ Wb,
    const float* __restrict__ wsb, const float* __restrict__ av,
    float* __restrict__ eout)
{
  __shared__ __attribute__((aligned(16))) unsigned short As[128 * 128];
  __shared__ __attribute__((aligned(16))) unsigned short Bs[2][16384];
  __shared__ float red[4][128];

  const int tid  = threadIdx.x;
  const int w    = tid >> 6;
  const int lane = tid & 63;
  const int lr   = lane & 15, lg = lane >> 4;
  const int wm   = w >> 2, wn = w & 3;        // wave grid 2(m) x 4(n)
  const int m0   = blockIdx.x * 128;
  const int bb   = m0 >> 11;

  f32x4 acc[4][8];
  #pragma unroll
  for (int i = 0; i < 4; ++i)
    #pragma unroll
    for (int j = 0; j < 8; ++j)
      #pragma unroll
      for (int r = 0; r < 4; ++r) acc[i][j][r] = 0.f;

  char* AsB = (char*)As;

  float4 a0[4], a1[4];
  auto issueA = [&](int s) {
    #pragma unroll
    for (int i = 0; i < 4; ++i) {
      int c = i * 512 + tid;
      int row = c >> 4, kq = c & 15;
      const float* gp = enc + ((size_t)(m0 + row) << 10) + (s << 7) + (kq << 3);
      a0[i] = *(const float4*)gp;
      a1[i] = *(const float4*)(gp + 4);
    }
  };
  auto writeA = [&]() {
    #pragma unroll
    for (int i = 0; i < 4; ++i) {
      int c = i * 512 + tid;
      int row = c >> 4, kq = c & 15;
      uint4 pv;
      pv.x = pk2(a0[i].x, a0[i].y);
      pv.y = pk2(a0[i].z, a0[i].w);
      pv.z = pk2(a1[i].x, a1[i].y);
      pv.w = pk2(a1[i].z, a1[i].w);
      *(uint4*)(AsB + row * 256 + ((kq * 16) ^ ((row & 7) << 4))) = pv;
    }
  };

  uint4 bv[4];
  auto issueB = [&](int kt) {
    const uint4* g = (const uint4*)(Wb + kt * 16384) + tid;
    #pragma unroll
    for (int i = 0; i < 4; ++i) bv[i] = g[i * 512];
  };
  auto writeB = [&](int d) {
    uint4* p = (uint4*)(&Bs[d][0]) + tid;
    #pragma unroll
    for (int i = 0; i < 4; ++i) p[i * 512] = bv[i];
  };

  int arow256[4], aswz[4];
  #pragma unroll
  for (int fm = 0; fm < 4; ++fm) {
    int row = wm * 64 + fm * 16 + lr;
    arow256[fm] = row * 256;
    aswz[fm] = (row & 7) << 4;
  }
  int boff[8];
  #pragma unroll
  for (int fn = 0; fn < 8; ++fn)
    boff[fn] = lg * 8192 + (wn * 128 + fn * 16 + lr) * 16;

  issueA(0);
  writeA();
  issueB(0);
  writeB(0);
  __syncthreads();

  for (int kt = 0; kt < 32; ++kt) {
    const int buf = kt & 1;
    if (kt < 31) issueB(kt + 1);
    if ((kt & 3) == 2 && kt < 28) issueA((kt >> 2) + 1);

    const int klo = (kt & 3) * 64 + lg * 16;
    bf16x8 af[4];
    #pragma unroll
    for (int fm = 0; fm < 4; ++fm)
      af[fm] = *(const bf16x8*)(AsB + arow256[fm] + (klo ^ aswz[fm]));
    #pragma unroll
    for (int fn = 0; fn < 8; ++fn) {
      bf16x8 bf = *(const bf16x8*)((char*)&Bs[buf][0] + boff[fn]);
      #pragma unroll
      for (int fm = 0; fm < 4; ++fm)
        acc[fm][fn] = __builtin_amdgcn_mfma_f32_16x16x32_bf16(af[fm], bf, acc[fm][fn], 0, 0, 0);
    }
    if (kt < 31) writeB(buf ^ 1);
    if ((kt & 3) == 3 && kt < 31) {
      __syncthreads();
      writeA();
    }
    __syncthreads();
  }

  float cw_[8], cv_[8];
  #pragma unroll
  for (int fn = 0; fn < 8; ++fn) {
    int col = wn * 128 + fn * 16 + lr;
    cw_[fn] = wsb[bb * 512 + col];
    cv_[fn] = av[col];
  }
  #pragma unroll
  for (int fm = 0; fm < 4; ++fm) {
    #pragma unroll
    for (int r = 0; r < 4; ++r) {
      float v = 0.f;
      #pragma unroll
      for (int fn = 0; fn < 8; ++fn)
        v += cv_[fn] * tanh_f(acc[fm][fn][r] + cw_[fn]);
      v += __shfl_xor(v, 1); v += __shfl_xor(v, 2);
      v += __shfl_xor(v, 4); v += __shfl_xor(v, 8);
      if (lr == 0) red[wn][wm * 64 + fm * 16 + lg * 4 + r] = v;
    }
  }
  __syncthreads();
  if (tid < 128)
    eout[m0 + tid] = red[0][tid] + red[1][tid] + red[2][tid] + red[3][tid];
}

// ---------------------------------------------------------------------------
// K3: softmax over S per batch
__global__ __launch_bounds__(256) void k_attnsm(const float* __restrict__ e,
                                                float* __restrict__ attn) {
  int b = blockIdx.x, tid = threadIdx.x;
  __shared__ float sm[256];
  float ev[8]; float mx = -3.0e38f;
  #pragma unroll
  for (int i = 0; i < 8; ++i) {
    float v = e[b * 2048 + i * 256 + tid];
    ev[i] = v; mx = fmaxf(mx, v);
  }
  sm[tid] = mx; __syncthreads();
  for (int st = 128; st; st >>= 1) { if (tid < st) sm[tid] = fmaxf(sm[tid], sm[tid + st]); __syncthreads(); }
  mx = sm[0]; __syncthreads();
  float sum = 0.f;
  #pragma unroll
  for (int i = 0; i < 8; ++i) { ev[i] = __expf(ev[i] - mx); sum += ev[i]; }
  sm[tid] = sum; __syncthreads();
  for (int st = 128; st; st >>= 1) { if (tid < st) sm[tid] += sm[tid + st]; __syncthreads(); }
  float inv = 1.f / sm[0];
  #pragma unroll
  for (int i = 0; i < 8; ++i) attn[b * 2048 + i * 256 + tid] = ev[i] * inv;
}

// K4: context partials over 32 s-chunks of 64
__global__ __launch_bounds__(256) void k_ctx(const float* __restrict__ enc,
                                             const float* __restrict__ attn,
                                             float* __restrict__ cp) {
  int sc = blockIdx.x, b = blockIdx.y, tid = threadIdx.x;
  int e0 = tid * 4;
  float ax = 0.f, ay = 0.f, az = 0.f, aw = 0.f;
  const float* base = enc + ((size_t)b * 2048 + sc * 64) * 1024 + e0;
  const float* awt = attn + b * 2048 + sc * 64;
  #pragma unroll 8
  for (int s = 0; s < 64; ++s) {
    float wv = awt[s];
    float4 v = *(const float4*)(base + (size_t)s * 1024);
    ax += wv * v.x; ay += wv * v.y; az += wv * v.z; aw += wv * v.w;
  }
  float4 o; o.x = ax; o.y = ay; o.z = az; o.w = aw;
  *(float4*)(cp + ((size_t)sc * 64 + b) * 1024 + e0) = o;
}

// K5a: reduce context, build xb[b][k] (k<1024 ctx, 1024..1279 embed, 1280..1791 h0),
//      cw[b] = ctx·wh_vec + embed·wx_vec
__global__ __launch_bounds__(256) void k_xprep(const float* __restrict__ cp,
                                               const float* __restrict__ et,
                                               const int* __restrict__ dec,
                                               const float* __restrict__ h0,
                                               const float* __restrict__ whv,
                                               const float* __restrict__ wxv,
                                               float* __restrict__ xb,
                                               float* __restrict__ cw) {
  int b = blockIdx.x, tid = threadIdx.x;
  __shared__ float sm[256];
  float acc = 0.f;
  for (int j = tid; j < 1024; j += 256) {
    float s = 0.f;
    #pragma unroll
    for (int sc = 0; sc < 32; ++sc) s += cp[((size_t)sc * 64 + b) * 1024 + j];
    xb[b * 1792 + j] = s;
    acc += s * whv[j];
  }
  int e = dec[b];
  {
    int j = tid;
    float s = et[(size_t)e * 256 + j];
    xb[b * 1792 + 1024 + j] = s;
    acc += s * wxv[j];
  }
  for (int j = tid; j < 512; j += 256)
    xb[b * 1792 + 1280 + j] = h0[b * 512 + j];
  sm[tid] = acc; __syncthreads();
  for (int st = 128; st; st >>= 1) { if (tid < st) sm[tid] += sm[tid + st]; __syncthreads(); }
  if (!tid) cw[b] = sm[0];
}

// K5b: gate partials via MFMA. Block = 64 j-rows x 64 b, k-slab 448.
// gp[sl][b][j] = sum_{k in slab} W[j][k]*x[b][k]
__global__ __launch_bounds__(256, 2) void k_gates(const float* __restrict__ wih,
                                                  const float* __restrict__ whh,
                                                  const float* __restrict__ xb,
                                                  float* __restrict__ gp) {
  __shared__ __attribute__((aligned(16))) char Bs[56 * 1040];  // 58240 B
  const int tid = threadIdx.x;
  const int w = tid >> 6, lane = tid & 63, lr = lane & 15, lg = lane >> 4;
  const int j0 = blockIdx.x * 64;
  const int sl = blockIdx.y;
  const int k0 = sl * 448;

  #pragma unroll
  for (int i = 0; i < 16; ++i) {
    int slot = i * 256 + tid;
    int kq = slot & 63, n = slot >> 6;
    if (kq < 56) {
      const float4* p = (const float4*)(xb + n * 1792 + k0 + kq * 8);
      float4 x0 = p[0], x1 = p[1];
      uint4 pv;
      pv.x = pk2(x0.x, x0.y); pv.y = pk2(x0.z, x0.w);
      pv.z = pk2(x1.x, x1.y); pv.w = pk2(x1.z, x1.w);
      *(uint4*)(Bs + kq * 1040 + n * 16) = pv;
    }
  }
  __syncthreads();

  f32x4 acc[4];
  #pragma unroll
  for (int fn = 0; fn < 4; ++fn)
    #pragma unroll
    for (int r = 0; r < 4; ++r) acc[fn][r] = 0.f;

  const int j = j0 + w * 16 + lr;
  for (int ks = 0; ks < 14; ++ks) {
    int kg = k0 + ks * 32 + lg * 8;
    const float* ap = (kg < 1280) ? (wih + (size_t)j * 1280 + kg)
                                  : (whh + (size_t)j * 512 + (kg - 1280));
    float4 x0 = *(const float4*)ap, x1 = *(const float4*)(ap + 4);
    bf16x8 af;
    unsigned* au = (unsigned*)&af;
    au[0] = pk2(x0.x, x0.y); au[1] = pk2(x0.z, x0.w);
    au[2] = pk2(x1.x, x1.y); au[3] = pk2(x1.z, x1.w);
    #pragma unroll
    for (int fn = 0; fn < 4; ++fn) {
      bf16x8 bf = *(const bf16x8*)(Bs + (ks * 4 + lg) * 1040 + (fn * 16 + lr) * 16);
      acc[fn] = __builtin_amdgcn_mfma_f32_16x16x32_bf16(af, bf, acc[fn], 0, 0, 0);
    }
  }
  #pragma unroll
  for (int fn = 0; fn < 4; ++fn) {
    int b = fn * 16 + lr;
    #pragma unroll
    for (int r = 0; r < 4; ++r) {
      int jr = j0 + w * 16 + lg * 4 + r;
      gp[((size_t)sl * 64 + b) * 2048 + jr] = acc[fn][r];
    }
  }
}

// K5c: LSTM cell + h_t,c_t outputs + p_gen (reduce 4 k-slabs)
__global__ __launch_bounds__(512) void k_lstm(const float* __restrict__ gp,
                                              const float* __restrict__ bih,
                                              const float* __restrict__ bhh,
                                              const float* __restrict__ c0,
                                              const float* __restrict__ cw,
                                              const float* __restrict__ wsv,
                                              float* __restrict__ dout,
                                              float* __restrict__ pg) {
  int b = blockIdx.x, h = threadIdx.x;
  __shared__ float sm[512];
  float gi = bih[h]        + bhh[h];
  float gf = bih[512 + h]  + bhh[512 + h];
  float gg = bih[1024 + h] + bhh[1024 + h];
  float go = bih[1536 + h] + bhh[1536 + h];
  #pragma unroll
  for (int kc = 0; kc < 4; ++kc) {
    const float* g = gp + ((size_t)kc * 64 + b) * 2048;
    gi += g[h]; gf += g[512 + h]; gg += g[1024 + h]; go += g[1536 + h];
  }
  float c  = sigm(gf) * c0[b * 512 + h] + sigm(gi) * tanh_f(gg);
  float ht = sigm(go) * tanh_f(c);
  dout[(size_t)B_ * V_ + b * 512 + h] = ht;
  dout[(size_t)B_ * V_ + B_ * H_ + b * 512 + h] = c;
  sm[h] = ht * wsv[h];
  __syncthreads();
  for (int st = 256; st; st >>= 1) { if (h < st) sm[h] += sm[h + st]; __syncthreads(); }
  if (!h) pg[b] = sigm(cw[b] + sm[0]);
}

// K6: vocab logits via MFMA. Block = 128 v-rows x all 64 batches.
// A = v_w rows (fp32->bf16 in reg, direct from global), B = ht staged in LDS.
__global__ __launch_bounds__(256, 2) void k_logits(const float* __restrict__ vw,
                                                   const float* __restrict__ vb,
                                                   const float* __restrict__ ht,
                                                   float* __restrict__ out) {
  __shared__ __attribute__((aligned(16))) char Bs[64 * 1040];  // 66560 B
  const int tid = threadIdx.x;
  const int w = tid >> 6, lane = tid & 63, lr = lane & 15, lg = lane >> 4;
  const int v0 = blockIdx.x * 128;

  // stage ht[64][512] -> bf16 [kq][n][8], kq-stride 1040 B (bank-spread)
  #pragma unroll
  for (int i = 0; i < 16; ++i) {
    int slot = i * 256 + tid;
    int kq = slot & 63, n = slot >> 6;
    const float4* p = (const float4*)(ht + n * 512 + kq * 8);
    float4 x0 = p[0], x1 = p[1];
    uint4 pv;
    pv.x = pk2(x0.x, x0.y); pv.y = pk2(x0.z, x0.w);
    pv.z = pk2(x1.x, x1.y); pv.w = pk2(x1.z, x1.w);
    *(uint4*)(Bs + kq * 1040 + n * 16) = pv;
  }
  __syncthreads();

  f32x4 acc[2][4];
  #pragma unroll
  for (int fm = 0; fm < 2; ++fm)
    #pragma unroll
    for (int fn = 0; fn < 4; ++fn)
      #pragma unroll
      for (int r = 0; r < 4; ++r) acc[fm][fn][r] = 0.f;

  int row0 = v0 + w * 32 + lr;
  int row1 = row0 + 16;
  const float* a0p = vw + (size_t)min(row0, V_ - 1) * 512 + lg * 8;
  const float* a1p = vw + (size_t)min(row1, V_ - 1) * 512 + lg * 8;

  float4 pa0[2], pa1[2];
  pa0[0] = *(const float4*)a0p; pa0[1] = *(const float4*)(a0p + 4);
  pa1[0] = *(const float4*)a1p; pa1[1] = *(const float4*)(a1p + 4);

  for (int ks = 0; ks < 16; ++ks) {
    bf16x8 af0, af1;
    {
      unsigned* u = (unsigned*)&af0;
      u[0] = pk2(pa0[0].x, pa0[0].y); u[1] = pk2(pa0[0].z, pa0[0].w);
      u[2] = pk2(pa0[1].x, pa0[1].y); u[3] = pk2(pa0[1].z, pa0[1].w);
      unsigned* v = (unsigned*)&af1;
      v[0] = pk2(pa1[0].x, pa1[0].y); v[1] = pk2(pa1[0].z, pa1[0].w);
      v[2] = pk2(pa1[1].x, pa1[1].y); v[3] = pk2(pa1[1].z, pa1[1].w);
    }
    if (ks < 15) {                       // prefetch next k-step
      const float* n0 = a0p + (ks + 1) * 32;
      const float* n1 = a1p + (ks + 1) * 32;
      pa0[0] = *(const float4*)n0; pa0[1] = *(const float4*)(n0 + 4);
      pa1[0] = *(const float4*)n1; pa1[1] = *(const float4*)(n1 + 4);
    }
    const char* bbase = Bs + (ks * 4 + lg) * 1040 + lr * 16;
    #pragma unroll
    for (int fn = 0; fn < 4; ++fn) {
      bf16x8 bf = *(const bf16x8*)(bbase + fn * 256);
      acc[0][fn] = __builtin_amdgcn_mfma_f32_16x16x32_bf16(af0, bf, acc[0][fn], 0, 0, 0);
      acc[1][fn] = __builtin_amdgcn_mfma_f32_16x16x32_bf16(af1, bf, acc[1][fn], 0, 0, 0);
    }
  }

  #pragma unroll
  for (int fm = 0; fm < 2; ++fm) {
    #pragma unroll
    for (int r = 0; r < 4; ++r) {
      int vrow = v0 + w * 32 + fm * 16 + lg * 4 + r;
      if (vrow < V_) {
        float bias = vb[vrow];
        #pragma unroll
        for (int fn = 0; fn < 4; ++fn) {
          int b = fn * 16 + lr;
          out[(size_t)b * V_ + vrow] = acc[fm][fn][r] + bias;
        }
      }
    }
  }
}

// K7a: per-(chunk,batch) softmax partials over V
#define VCH 6283
__global__ __launch_bounds__(256) void k_sm1(const float* __restrict__ out,
                                             float* __restrict__ pst) {
  int c = blockIdx.x, b = blockIdx.y, tid = threadIdx.x;
  __shared__ float sm[256];
  const float* row = out + (size_t)b * V_;
  int v0 = c * VCH, v1 = min(v0 + VCH, V_);
  float mx = -3.0e38f;
  for (int v = v0 + tid; v < v1; v += 256) mx = fmaxf(mx, row[v]);
  sm[tid] = mx; __syncthreads();
  for (int st = 128; st; st >>= 1) { if (tid < st) sm[tid] = fmaxf(sm[tid], sm[tid + st]); __syncthreads(); }
  mx = sm[0]; __syncthreads();
  float sum = 0.f;
  for (int v = v0 + tid; v < v1; v += 256) sum += __expf(row[v] - mx);
  sm[tid] = sum; __syncthreads();
  for (int st = 128; st; st >>= 1) { if (tid < st) sm[tid] += sm[tid + st]; __syncthreads(); }
  if (!tid) { pst[(b * 8 + c) * 2] = mx; pst[(b * 8 + c) * 2 + 1] = sm[0]; }
}

// K7b: merge chunk partials
__global__ __launch_bounds__(64) void k_sm2(const float* __restrict__ pst,
                                            float* __restrict__ stats) {
  int b = threadIdx.x;
  float mx = -3.0e38f;
  #pragma unroll
  for (int c = 0; c < 8; ++c) mx = fmaxf(mx, pst[(b * 8 + c) * 2]);
  float s = 0.f;
  #pragma unroll
  for (int c = 0; c < 8; ++c)
    s += pst[(b * 8 + c) * 2 + 1] * __expf(pst[(b * 8 + c) * 2] - mx);
  stats[b * 2] = mx; stats[b * 2 + 1] = s;
}

// K8: out = p_gen * softmax(logits) in place
__global__ __launch_bounds__(256) void k_final(float* __restrict__ out,
                                               const float* __restrict__ stats,
                                               const float* __restrict__ pg) {
  int v = blockIdx.x * 256 + threadIdx.x;
  int b = blockIdx.y;
  if (v < V_) {
    float mx = stats[b * 2];
    float scale = pg[b] / stats[b * 2 + 1];
    size_t i = (size_t)b * V_ + v;
    out[i] = scale * __expf(out[i] - mx);
  }
}

// K9: scatter attention into vocab
__global__ __launch_bounds__(256) void k_scatter(float* __restrict__ out,
                                                 const float* __restrict__ attn,
                                                 const int* __restrict__ einp,
                                                 const float* __restrict__ pg) {
  int b = blockIdx.y;
  int s = blockIdx.x * 256 + threadIdx.x;
  int v = einp[b * 2048 + s];
  float w = (1.f - pg[b]) * attn[b * 2048 + s];
  atomicAdd(out + (size_t)b * V_ + v, w);
}

// ---------------------------------------------------------------------------
extern "C" void kernel_launch(void* const* d_in, const int* in_sizes, int n_in,
                              void* d_out, int out_size, void* d_ws, size_t ws_size,
                              hipStream_t stream) {
  const float* enc  = (const float*)d_in[0];
  const float* h0   = (const float*)d_in[1];
  const float* c0   = (const float*)d_in[2];
  const int*   dec  = (const int*)d_in[3];
  const int*   einp = (const int*)d_in[4];
  const float* et   = (const float*)d_in[5];
  const float* whw  = (const float*)d_in[6];
  const float* whb  = (const float*)d_in[7];
  const float* wsw  = (const float*)d_in[8];
  const float* wsbv = (const float*)d_in[9];
  const float* av   = (const float*)d_in[10];
  const float* wih  = (const float*)d_in[11];
  const float* whh  = (const float*)d_in[12];
  const float* bih  = (const float*)d_in[13];
  const float* bhh  = (const float*)d_in[14];
  const float* whv  = (const float*)d_in[15];
  const float* wsv  = (const float*)d_in[16];
  const float* wxv  = (const float*)d_in[17];
  const float* vw   = (const float*)d_in[18];
  const float* vb   = (const float*)d_in[19];
  float* out = (float*)d_out;

  char* ws = (char*)d_ws;
  unsigned short* Wb = (unsigned short*)(ws + 0);        // 1,048,576
  float* wsbt  = (float*)(ws + 1048576);                 //   131,072
  float* e     = (float*)(ws + 1179648);                 //   524,288
  float* attn  = (float*)(ws + 1703936);                 //   524,288
  float* cpgp  = (float*)(ws + 2228224);                 // 8,388,608 (cp, then gp)
  float* xb    = (float*)(ws + 10616832);                //   458,752
  float* cw    = (float*)(ws + 11075584);                //       256
  float* pg    = (float*)(ws + 11075840);                //       256
  float* stats = (float*)(ws + 11076096);                //       512
  float* pst   = (float*)(ws + 11076608);                //     4,096

  k_convw  <<<2048, 256, 0, stream>>>(whw, Wb);
  k_wsapp  <<<128, 256, 0, stream>>>(h0, wsw, wsbv, whb, wsbt);
  k_energy <<<1024, 512, 0, stream>>>(enc, Wb, wsbt, av, e);
  k_attnsm <<<64, 256, 0, stream>>>(e, attn);
  k_ctx    <<<dim3(32, 64), 256, 0, stream>>>(enc, attn, cpgp);
  k_xprep  <<<64, 256, 0, stream>>>(cpgp, et, dec, h0, whv, wxv, xb, cw);
  k_gates  <<<dim3(32, 4), 256, 0, stream>>>(wih, whh, xb, cpgp);
  k_lstm   <<<64, 512, 0, stream>>>(cpgp, bih, bhh, c0, cw, wsv, out, pg);
  k_logits <<<393, 256, 0, stream>>>(vw, vb, out + (size_t)B_ * V_, out);
  k_sm1    <<<dim3(8, 64), 256, 0, stream>>>(out, pst);
  k_sm2    <<<1, 64, 0, stream>>>(pst, stats);
  k_final  <<<dim3(197, 64), 256, 0, stream>>>(out, stats, pg);
  k_scatter<<<dim3(8, 64), 256, 0, stream>>>(out, attn, einp, pg);
}